// Round 14
// baseline (209.852 us; speedup 1.0000x reference)
//
#include <hip/hip_runtime.h>
#include <hip/hip_bf16.h>

typedef __bf16 bf16;
typedef __bf16 bf16x4 __attribute__((ext_vector_type(4)));
typedef __bf16 bf16x8 __attribute__((ext_vector_type(8)));
typedef float f32x4 __attribute__((ext_vector_type(4)));

#define N_NODES 131072
#define CH      512
#define HD      128
#define LMAX    8192
#define NG      16

typedef __attribute__((address_space(3))) unsigned int lds_u32;
typedef __attribute__((address_space(1))) const unsigned int g_u32;

__device__ __forceinline__ void gload16(const void* gp, void* lp) {
    __builtin_amdgcn_global_load_lds((g_u32*)gp, (lds_u32*)lp, 16, 0, 0);
}

// ---------------- K0: W (3x128x512 fp32) -> bf16, BK=64 staging order, granule-XOR swizzled ----
// wsW granule layout: [c=8][j=384][g=8] of 8 elems; value = W3[j][c*64 + ((g ^ (j&7))<<3) + e]
// K1 B-read: element (kk + lh*8) ^ ((j&7)<<3) -> 2 rows/granule-slot = conflict-free.
__global__ __launch_bounds__(256, 1) void k0_prep(
    const float* __restrict__ Wq, const float* __restrict__ Wk,
    const float* __restrict__ Wv, bf16* __restrict__ wsW)
{
    int t = blockIdx.x * 256 + threadIdx.x;      // 24576 granules of 8 elements
    int c = t / 3072;                            // K-chunk (BK=64)
    int r = t % 3072;
    int j = r >> 3, g = r & 7;
    const float* Wrow = (j < 128) ? (Wq + (size_t)j * CH)
                       : (j < 256) ? (Wk + (size_t)(j - 128) * CH)
                                   : (Wv + (size_t)(j - 256) * CH);
    int col0 = (g ^ (j & 7)) << 3;
    const float* src = Wrow + c * 64 + col0;
    float4 f0 = *(const float4*)src;
    float4 f1 = *(const float4*)(src + 4);
    bf16x8 o;
    o[0] = (bf16)f0.x; o[1] = (bf16)f0.y; o[2] = (bf16)f0.z; o[3] = (bf16)f0.w;
    o[4] = (bf16)f1.x; o[5] = (bf16)f1.y; o[6] = (bf16)f1.z; o[7] = (bf16)f1.w;
    *(bf16x8*)(wsW + (size_t)t * 8) = o;
}

// ---------------- K1: QKV projection, 64x384 tile, ALL-gload_lds staging ----------------
// grid 2048 x 256 (4 waves). LDS 66 KB -> 2 blocks/CU. A staged as FP32 via gload_lds
// (dbuf [2][64][32] f32, per-lane pre-swizzled source, granule-XOR conflict-free reads);
// B single-buffered [384][64] bf16 (refreshed every 2 iters from pre-swizzled wsW).
// gload_lds prefetch cannot be sunk by the compiler -> true async staging.
__global__ __launch_bounds__(256, 1) void k1_proj(
    const float* __restrict__ x, const bf16* __restrict__ wsW,
    bf16* __restrict__ qo, bf16* __restrict__ ko, bf16* __restrict__ vo,
    float* __restrict__ sumsq)
{
    __shared__ float A32[2][2048];    // [2][64 rows][32 f32] = 16,384 B
    __shared__ bf16 Bs[24576];        // [384][64] = 49,152 B (swizzled content)
    __shared__ float rq[4], rk[4];

    const int tid = threadIdx.x;
    const int lane = tid & 63;
    const int w = tid >> 6;                     // wave w -> output cols w*96..w*96+95
    const int lr = lane & 15, lh = lane >> 4;
    const int n0 = blockIdx.x * 64;

    // A-staging per-lane constants: call jc covers rows jc*8..jc*8+7, 8 lanes/row.
    const int as_row = lane >> 3;                           // row within call (== r&7)
    const int as_col = (((lane & 7) ^ as_row) << 2);        // swizzled f32 col (granule XOR)
    const size_t abase = (size_t)(n0 + as_row) * CH + as_col;   // + jc*8*CH + a*32

    f32x4 acc[4][6];
    #pragma unroll
    for (int mi = 0; mi < 4; mi++)
        #pragma unroll
        for (int ni = 0; ni < 6; ni++)
            acc[mi][ni] = (f32x4){0.f, 0.f, 0.f, 0.f};

    // prologue: stage B(0) + A(0), one drain
    {
        const char* wb = (const char*)wsW + w * 1024 + lane * 16;
        char* db = (char*)Bs + w * 1024;
        #pragma unroll
        for (int i = 0; i < 12; i++) gload16(wb + i * 4096, db + i * 4096);
        #pragma unroll
        for (int i = 0; i < 2; i++) {
            int jc = w * 2 + i;
            gload16((const char*)(x + abase + (size_t)jc * 8 * CH),
                    (char*)&A32[0][jc * 256]);
        }
        __syncthreads();
    }

    for (int a = 0; a < 16; a++) {               // 16 K-chunks of 32 (B refreshed per 2)
        const int cur = a & 1, nxt = cur ^ 1;
        const int kk = (a & 1) * 32;             // K-offset within current B-chunk
        if (a < 15) {                            // async prefetch A(a+1) -> A32[nxt]
            #pragma unroll
            for (int i = 0; i < 2; i++) {
                int jc = w * 2 + i;
                gload16((const char*)(x + abase + (size_t)jc * 8 * CH + (a + 1) * 32),
                        (char*)&A32[nxt][jc * 256]);
            }
        }
        // build A-frags: fp32 LDS reads (granule-XOR, conflict-free) + cvt to bf16
        bf16x8 af[4];
        #pragma unroll
        for (int mi = 0; mi < 4; mi++) {
            int r = mi * 16 + lr;
            int base = r * 32;
            f32x4 lo = *(const f32x4*)&A32[cur][base + ((( lh * 2     ) ^ (lr & 7)) << 2)];
            f32x4 hi = *(const f32x4*)&A32[cur][base + (((lh * 2 + 1) ^ (lr & 7)) << 2)];
            bf16x8 t;
            t[0] = (bf16)lo[0]; t[1] = (bf16)lo[1]; t[2] = (bf16)lo[2]; t[3] = (bf16)lo[3];
            t[4] = (bf16)hi[0]; t[5] = (bf16)hi[1]; t[6] = (bf16)hi[2]; t[7] = (bf16)hi[3];
            af[mi] = t;
        }
        // B-read-once (ni outer), 24 MFMAs
        #pragma unroll
        for (int ni = 0; ni < 6; ni++) {
            int j = w * 96 + ni * 16 + lr;
            bf16x8 bf_ = *(const bf16x8*)&Bs[j * 64 + ((kk + lh * 8) ^ ((j & 7) << 3))];
            #pragma unroll
            for (int mi = 0; mi < 4; mi++)
                acc[mi][ni] = __builtin_amdgcn_mfma_f32_16x16x32_bf16(
                    af[mi], bf_, acc[mi][ni], 0, 0, 0);
        }
        __syncthreads();   // drains A(a+1) gloads; closes Bs/A32[cur] read window
        if ((a & 1) && a < 15) {                 // refresh B for next 64-K chunk
            const char* wb = (const char*)wsW + (size_t)((a >> 1) + 1) * 49152
                           + w * 1024 + lane * 16;
            char* db = (char*)Bs + w * 1024;
            #pragma unroll
            for (int i = 0; i < 12; i++) gload16(wb + i * 4096, db + i * 4096);
            __syncthreads();   // drain (other co-resident block computes meanwhile)
        }
    }

    // epilogue: write bf16 q/k/v + sum of squares (fp32, pre-quantization)
    float sq = 0.f, sk = 0.f;
    #pragma unroll
    for (int mi = 0; mi < 4; mi++) {
        #pragma unroll
        for (int ni = 0; ni < 6; ni++) {
            int col = w * 96 + ni * 16 + lr;    // 16-wide frags never cross a 128 boundary
            int arr = col >> 7, cc = col & 127;
            bf16* dst = (arr == 0) ? qo : (arr == 1) ? ko : vo;
            #pragma unroll
            for (int r = 0; r < 4; r++) {
                int row = n0 + mi * 16 + lh * 4 + r;
                float val = acc[mi][ni][r];
                dst[(size_t)row * HD + cc] = (bf16)val;
                if (arr == 0) sq += val * val;
                else if (arr == 1) sk += val * val;
            }
        }
    }
    #pragma unroll
    for (int off = 32; off > 0; off >>= 1) {
        sq += __shfl_down(sq, off);
        sk += __shfl_down(sk, off);
    }
    if (lane == 0) { rq[w] = sq; rk[w] = sk; }
    __syncthreads();
    if (tid == 0) {
        float a = 0.f, b = 0.f;
        #pragma unroll
        for (int i = 0; i < 4; i++) { a += rq[i]; b += rk[i]; }
        atomicAdd(&sumsq[0], a);
        atomicAdd(&sumsq[1], b);
    }
}

// ---------------- K2: per-graph k^T v via MFMA (node-dim as K) ----------------
// grid 256 blocks (16 graphs x 16 chunks of 512 rows) x 512 threads (8 waves, 2x4).
__global__ __launch_bounds__(512, 1) void k2_kv(
    const bf16* __restrict__ ko, const bf16* __restrict__ vo,
    float* __restrict__ part_kv, float* __restrict__ part_ks)
{
    __shared__ __align__(16) char smem[16640];   // kt[32][130] | vt[32][130]; reused as f32 scr
    bf16 (*kt)[130] = (bf16(*)[130])smem;
    bf16 (*vt)[130] = (bf16(*)[130])(smem + 8320);
    float* scr = (float*)smem;

    const int tid = threadIdx.x, lane = tid & 63, w = tid >> 6;
    const int wr = w >> 2, wc = w & 3;           // 2 m-groups x 4 d-groups
    const int lr = lane & 15, lh = lane >> 4;
    const int b = blockIdx.x >> 4, cch = blockIdx.x & 15;
    const size_t l0 = (size_t)b * LMAX + (size_t)cch * 512;
    const int sr = tid >> 4, sc = tid & 15;      // staging row / col8

    f32x4 acc[4][2];
    #pragma unroll
    for (int mi = 0; mi < 4; mi++)
        #pragma unroll
        for (int ni = 0; ni < 2; ni++)
            acc[mi][ni] = (f32x4){0.f, 0.f, 0.f, 0.f};
    float ks8[8] = {};

    uint4 kk4 = *(const uint4*)&ko[(l0 + sr) * HD + sc * 8];
    uint4 vv4 = *(const uint4*)&vo[(l0 + sr) * HD + sc * 8];

    for (int lt = 0; lt < 512; lt += 32) {
        __syncthreads();   // prev compute done
        #pragma unroll
        for (int j2 = 0; j2 < 4; j2++) {
            *(unsigned int*)&kt[sr][sc * 8 + j2 * 2] = ((const unsigned int*)&kk4)[j2];
            *(unsigned int*)&vt[sr][sc * 8 + j2 * 2] = ((const unsigned int*)&vv4)[j2];
        }
        #pragma unroll
        for (int j = 0; j < 8; j++) ks8[j] += (float)((const bf16*)&kk4)[j];
        __syncthreads();   // tiles published
        if (lt + 32 < 512) {   // prefetch next tile during compute
            kk4 = *(const uint4*)&ko[(l0 + lt + 32 + sr) * HD + sc * 8];
            vv4 = *(const uint4*)&vo[(l0 + lt + 32 + sr) * HD + sc * 8];
        }
        bf16x8 a[4], bb[2];
        #pragma unroll
        for (int mi = 0; mi < 4; mi++) {
            int m = wr * 64 + mi * 16 + lr;
            #pragma unroll
            for (int j = 0; j < 8; j++) a[mi][j] = kt[lh * 8 + j][m];
        }
        #pragma unroll
        for (int ni = 0; ni < 2; ni++) {
            int d = wc * 32 + ni * 16 + lr;
            #pragma unroll
            for (int j = 0; j < 8; j++) bb[ni][j] = vt[lh * 8 + j][d];
        }
        #pragma unroll
        for (int mi = 0; mi < 4; mi++)
            #pragma unroll
            for (int ni = 0; ni < 2; ni++)
                acc[mi][ni] = __builtin_amdgcn_mfma_f32_16x16x32_bf16(
                    a[mi], bb[ni], acc[mi][ni], 0, 0, 0);
    }

    // ks partial: reduce per-thread col-sums across the 32 row-groups
    __syncthreads();
    #pragma unroll
    for (int j = 0; j < 8; j++) scr[tid * 8 + j] = ks8[j];
    __syncthreads();
    if (tid < 128) {
        float s = 0.f;
        #pragma unroll
        for (int g = 0; g < 32; g++)
            s += scr[((g << 4) | (tid >> 3)) * 8 + (tid & 7)];
        part_ks[blockIdx.x * HD + tid] = s;
    }

    float* dst = part_kv + (size_t)blockIdx.x * 16384;
    #pragma unroll
    for (int mi = 0; mi < 4; mi++)
        #pragma unroll
        for (int ni = 0; ni < 2; ni++)
            #pragma unroll
            for (int r = 0; r < 4; r++) {
                int m = wr * 64 + mi * 16 + lh * 4 + r;
                int d = wc * 32 + ni * 16 + lr;
                dst[m * HD + d] = acc[mi][ni][r];
            }
}

// ---------------- K2b: reduce 16 partials/graph, apply s_q*s_k, write kvs^T ----------------
__global__ __launch_bounds__(256, 1) void k2b_reduce(
    const float* __restrict__ part_kv, const float* __restrict__ part_ks,
    const float* __restrict__ sumsq,
    bf16* __restrict__ kvsT, float* __restrict__ ks_sum_s)
{
    const int b = blockIdx.x >> 3, ms = blockIdx.x & 7, tid = threadIdx.x;
    const float s_qk = rsqrtf(sumsq[0]) * rsqrtf(sumsq[1]);

    #pragma unroll
    for (int i = 0; i < 8; i++) {
        int idx = i * 256 + tid;               // 2048 outputs for this m-slice
        int m = ms * 16 + (idx >> 7), d = idx & 127;
        float s = 0.f;
        #pragma unroll
        for (int c = 0; c < 16; c++)
            s += part_kv[((size_t)(b * 16 + c) << 14) + (m << 7) + d];
        kvsT[((size_t)b << 14) + (d << 7) + m] = (bf16)(s * s_qk);
    }
    if (ms == 0 && tid < 128) {
        float s = 0.f;
        #pragma unroll
        for (int c = 0; c < 16; c++)
            s += part_ks[(b * 16 + c) * HD + tid];
        ks_sum_s[b * HD + tid] = s * s_qk;
    }
}

// ---------------- K3: out = (q @ kvsT + 16 v) / (q . ks_sum_s + 16) ----------------
// 70 KB LDS -> 2 blocks/CU; kvsT B-frags read direct from global (L2-hot, 32 KB/graph).
__global__ __launch_bounds__(256, 2) void k3_out(
    const bf16* __restrict__ qo, const bf16* __restrict__ vo,
    const bf16* __restrict__ kvsT, const float* __restrict__ ks_sum_s,
    float* __restrict__ out)
{
    __shared__ bf16 qs[128][136];
    __shared__ bf16 vsh[128][136];
    __shared__ float kss[128];
    __shared__ float denom[128];
    const int tid = threadIdx.x, lane = tid & 63, w = tid >> 6;
    const int lr = lane & 15, lh = lane >> 4;
    const int n0 = blockIdx.x * 128;
    const int b = n0 >> 13;

    #pragma unroll
    for (int i = 0; i < 8; i++) {
        int idx = tid + i * 256;
        int r = idx >> 4, c8 = idx & 15;
        *(bf16x8*)&qs[r][c8 * 8]  = *(const bf16x8*)&qo[(size_t)(n0 + r) * HD + c8 * 8];
        *(bf16x8*)&vsh[r][c8 * 8] = *(const bf16x8*)&vo[(size_t)(n0 + r) * HD + c8 * 8];
    }
    if (tid < 128) kss[tid] = ks_sum_s[b * HD + tid];
    __syncthreads();

    if (tid < 128) {
        float s = 0.f;
        #pragma unroll 8
        for (int m = 0; m < HD; m++) s += (float)qs[tid][m] * kss[m];
        denom[tid] = s + 16.0f;
    }

    f32x4 acc[2][8];
    #pragma unroll
    for (int mi = 0; mi < 2; mi++)
        #pragma unroll
        for (int ni = 0; ni < 8; ni++)
            acc[mi][ni] = (f32x4){0.f, 0.f, 0.f, 0.f};

    #pragma unroll
    for (int k0 = 0; k0 < HD; k0 += 32) {
        bf16x8 a[2], bb[8];
        #pragma unroll
        for (int mi = 0; mi < 2; mi++)
            a[mi] = *(const bf16x8*)&qs[w * 32 + mi * 16 + lr][k0 + lh * 8];
        #pragma unroll
        for (int ni = 0; ni < 8; ni++)
            bb[ni] = *(const bf16x8*)&kvsT[(size_t)b * 16384 + (size_t)(ni * 16 + lr) * HD + k0 + lh * 8];
        #pragma unroll
        for (int mi = 0; mi < 2; mi++)
            #pragma unroll
            for (int ni = 0; ni < 8; ni++)
                acc[mi][ni] = __builtin_amdgcn_mfma_f32_16x16x32_bf16(
                    a[mi], bb[ni], acc[mi][ni], 0, 0, 0);
    }
    __syncthreads();   // denom ready

    #pragma unroll
    for (int mi = 0; mi < 2; mi++) {
        #pragma unroll
        for (int ni = 0; ni < 8; ni++) {
            int col = ni * 16 + lr;
            #pragma unroll
            for (int r = 0; r < 4; r++) {
                int row = w * 32 + mi * 16 + lh * 4 + r;
                float vv = (float)vsh[row][col];
                out[(size_t)(n0 + row) * HD + col] =
                    (acc[mi][ni][r] + 16.0f * vv) / denom[row];
            }
        }
    }
}

// ---------------- launch ----------------
extern "C" void kernel_launch(void* const* d_in, const int* in_sizes, int n_in,
                              void* d_out, int out_size, void* d_ws, size_t ws_size,
                              hipStream_t stream)
{
    const float* x  = (const float*)d_in[0];
    const float* Wq = (const float*)d_in[1];
    const float* Wk = (const float*)d_in[2];
    const float* Wv = (const float*)d_in[3];

    char* ws = (char*)d_ws;
    const size_t Q_OFF   = 0;                       // 131072*128*2 = 33554432
    const size_t K_OFF   = 33554432;
    const size_t V_OFF   = 67108864;
    const size_t PKV_OFF = 100663296;               // 256*16384*4 = 16777216
    const size_t PKS_OFF = 117440512;               // 256*128*4   = 131072
    const size_t KVS_OFF = 117571584;               // 16*16384*2  = 524288
    const size_t KSS_OFF = 118095872;               // 16*128*4    = 8192
    const size_t SSQ_OFF = 118104064;               // 2*4
    const size_t NEED    = 118104072;
    if (ws_size < NEED) return;

    bf16*  qo      = (bf16*)(ws + Q_OFF);
    bf16*  ko      = (bf16*)(ws + K_OFF);
    bf16*  vo      = (bf16*)(ws + V_OFF);
    float* part_kv = (float*)(ws + PKV_OFF);
    float* part_ks = (float*)(ws + PKS_OFF);
    bf16*  kvsT    = (bf16*)(ws + KVS_OFF);
    float* ks_sum  = (float*)(ws + KSS_OFF);
    float* sumsq   = (float*)(ws + SSQ_OFF);
    // wsW (393216 B) overlaps part_kv region: live only k0->k1, dead before k2 writes part_kv
    bf16*  wsW     = (bf16*)(ws + PKV_OFF);

    hipMemsetAsync(sumsq, 0, 8, stream);
    k0_prep<<<dim3(96), dim3(256), 0, stream>>>(Wq, Wk, Wv, wsW);
    k1_proj<<<dim3(N_NODES / 64), dim3(256), 0, stream>>>(x, wsW, qo, ko, vo, sumsq);
    k2_kv<<<dim3(256), dim3(512), 0, stream>>>(ko, vo, part_kv, part_ks);
    k2b_reduce<<<dim3(128), dim3(256), 0, stream>>>(part_kv, part_ks, sumsq, kvsT, ks_sum);
    k3_out<<<dim3(N_NODES / 128), dim3(256), 0, stream>>>(qo, vo, kvsT, ks_sum, (float*)d_out);
}

// Round 15
// 202.245 us; speedup vs baseline: 1.0376x; 1.0376x over previous
//
#include <hip/hip_runtime.h>
#include <hip/hip_bf16.h>

typedef __bf16 bf16;
typedef __bf16 bf16x4 __attribute__((ext_vector_type(4)));
typedef __bf16 bf16x8 __attribute__((ext_vector_type(8)));
typedef float f32x4 __attribute__((ext_vector_type(4)));

#define N_NODES 131072
#define CH      512
#define HD      128
#define LMAX    8192
#define NG      16

typedef __attribute__((address_space(3))) unsigned int lds_u32;
typedef __attribute__((address_space(1))) const unsigned int g_u32;

__device__ __forceinline__ void gload16(const void* gp, void* lp) {
    __builtin_amdgcn_global_load_lds((g_u32*)gp, (lds_u32*)lp, 16, 0, 0);
}

// ---------------- K0: W (3x128x512 fp32) -> bf16, BK=32 staging order, granule-XOR swizzled ----
// wsW granule layout: [c=16][j=384][g=4] of 8 elems; value = W3[j][c*32 + ((g ^ ((j>>1)&3))<<3) + e]
// K1 reads granule g = lh ^ ((j>>1)&3) to get cols lh*8..lh*8+7.  (refcheck'd in r13)
__global__ __launch_bounds__(256, 1) void k0_prep(
    const float* __restrict__ Wq, const float* __restrict__ Wk,
    const float* __restrict__ Wv, bf16* __restrict__ wsW)
{
    int t = blockIdx.x * 256 + threadIdx.x;      // 24576 granules of 8 elements
    int c = t / 1536;                            // K-chunk (BK=32)
    int r = t % 1536;
    int j = r >> 2, g = r & 3;
    const float* Wrow = (j < 128) ? (Wq + (size_t)j * CH)
                       : (j < 256) ? (Wk + (size_t)(j - 128) * CH)
                                   : (Wv + (size_t)(j - 256) * CH);
    int col0 = c * 32 + ((g ^ ((j >> 1) & 3)) << 3);
    float4 f0 = *(const float4*)(Wrow + col0);
    float4 f1 = *(const float4*)(Wrow + col0 + 4);
    bf16x8 o;
    o[0] = (bf16)f0.x; o[1] = (bf16)f0.y; o[2] = (bf16)f0.z; o[3] = (bf16)f0.w;
    o[4] = (bf16)f1.x; o[5] = (bf16)f1.y; o[6] = (bf16)f1.z; o[7] = (bf16)f1.w;
    *(bf16x8*)(wsW + (size_t)t * 8) = o;
}

// ---------------- K1: QKV projection, counted-vmcnt pipeline (T4) ----------------
// grid 2048 x 256 (4 waves). A fp32 dbuf [2][64][32] (gload_lds, granule-XOR; r14 layout),
// B bf16 dbuf [2][384][32] (gload_lds from pre-swizzled wsW; r13 layout). 66 KB -> 2 blk/CU.
// Loop: issue 8 prefetch gloads -> s_waitcnt vmcnt(8) (NOT 0) + s_barrier -> MFMA -> s_barrier.
// Prefetched loads stay in flight across barriers; no full drain in the main loop.
__global__ __launch_bounds__(256, 1) void k1_proj(
    const float* __restrict__ x, const bf16* __restrict__ wsW,
    bf16* __restrict__ qo, bf16* __restrict__ ko, bf16* __restrict__ vo,
    float* __restrict__ sumsq)
{
    __shared__ float A32[2][2048];    // 16,384 B
    __shared__ bf16 Bs[2][12288];     // 49,152 B (swizzled content)
    __shared__ float rq[4], rk[4];

    const int tid = threadIdx.x;
    const int lane = tid & 63;
    const int w = tid >> 6;                     // wave w -> output cols w*96..w*96+95
    const int lr = lane & 15, lh = lane >> 4;
    const int n0 = blockIdx.x * 64;

    // A-staging per-lane constants: call jc covers rows jc*8..jc*8+7, 8 lanes/row.
    const int as_row = lane >> 3;
    const int as_col = (((lane & 7) ^ as_row) << 2);        // swizzled f32 col
    const size_t abase = (size_t)(n0 + as_row) * CH + as_col;

    f32x4 acc[4][6];
    #pragma unroll
    for (int mi = 0; mi < 4; mi++)
        #pragma unroll
        for (int ni = 0; ni < 6; ni++)
            acc[mi][ni] = (f32x4){0.f, 0.f, 0.f, 0.f};

    // prologue: stage A(0) + B(0), full drain (once)
    {
        const char* wb = (const char*)wsW + w * 1024 + lane * 16;
        char* db = (char*)&Bs[0][0] + w * 1024;
        #pragma unroll
        for (int i = 0; i < 6; i++) gload16(wb + i * 4096, db + i * 4096);
        #pragma unroll
        for (int i = 0; i < 2; i++) {
            int jc = w * 2 + i;
            gload16((const char*)(x + abase + (size_t)jc * 8 * CH),
                    (char*)&A32[0][jc * 256]);
        }
        asm volatile("s_waitcnt vmcnt(0)\n\ts_barrier" ::: "memory");
        __builtin_amdgcn_sched_barrier(0);
    }

    for (int a = 0; a < 16; a++) {
        const int cur = a & 1, nxt = cur ^ 1;
        if (a < 15) {
            // issue prefetch(a+1): 6 B-gloads + 2 A-gloads = 8 in flight per wave
            const char* wb = (const char*)wsW + (size_t)(a + 1) * 24576 + w * 1024 + lane * 16;
            char* db = (char*)&Bs[nxt][0] + w * 1024;
            #pragma unroll
            for (int i = 0; i < 6; i++) gload16(wb + i * 4096, db + i * 4096);
            #pragma unroll
            for (int i = 0; i < 2; i++) {
                int jc = w * 2 + i;
                gload16((const char*)(x + abase + (size_t)jc * 8 * CH + (a + 1) * 32),
                        (char*)&A32[nxt][jc * 256]);
            }
            // wait ONLY for iter-a's 8 loads (issued last iter); keep the new 8 in flight
            asm volatile("s_waitcnt vmcnt(8)\n\ts_barrier" ::: "memory");
        } else {
            asm volatile("s_waitcnt vmcnt(0)\n\ts_barrier" ::: "memory");
        }
        __builtin_amdgcn_sched_barrier(0);

        // A-frags: fp32 LDS reads (granule-XOR) + cvt to bf16 (r14 pattern, refcheck'd)
        bf16x8 af[4];
        #pragma unroll
        for (int mi = 0; mi < 4; mi++) {
            int r = mi * 16 + lr;
            int base = r * 32;
            f32x4 lo = *(const f32x4*)&A32[cur][base + (((lh * 2    ) ^ (lr & 7)) << 2)];
            f32x4 hi = *(const f32x4*)&A32[cur][base + (((lh * 2 + 1) ^ (lr & 7)) << 2)];
            bf16x8 t;
            t[0] = (bf16)lo[0]; t[1] = (bf16)lo[1]; t[2] = (bf16)lo[2]; t[3] = (bf16)lo[3];
            t[4] = (bf16)hi[0]; t[5] = (bf16)hi[1]; t[6] = (bf16)hi[2]; t[7] = (bf16)hi[3];
            af[mi] = t;
        }
        // B-read-once (r13 pattern, refcheck'd), 24 MFMAs
        #pragma unroll
        for (int ni = 0; ni < 6; ni++) {
            int j = w * 96 + ni * 16 + lr;
            int g = lh ^ ((j >> 1) & 3);
            bf16x8 bf_ = *(const bf16x8*)&Bs[cur][j * 32 + (g << 3)];
            #pragma unroll
            for (int mi = 0; mi < 4; mi++)
                acc[mi][ni] = __builtin_amdgcn_mfma_f32_16x16x32_bf16(
                    af[mi], bf_, acc[mi][ni], 0, 0, 0);
        }
        // end-of-read fence: all waves done with buf[cur] before anyone prefetches into it
        asm volatile("s_barrier" ::: "memory");
        __builtin_amdgcn_sched_barrier(0);
    }

    // epilogue: write bf16 q/k/v + sum of squares (fp32, pre-quantization)
    float sq = 0.f, sk = 0.f;
    #pragma unroll
    for (int mi = 0; mi < 4; mi++) {
        #pragma unroll
        for (int ni = 0; ni < 6; ni++) {
            int col = w * 96 + ni * 16 + lr;    // 16-wide frags never cross a 128 boundary
            int arr = col >> 7, cc = col & 127;
            bf16* dst = (arr == 0) ? qo : (arr == 1) ? ko : vo;
            #pragma unroll
            for (int r = 0; r < 4; r++) {
                int row = n0 + mi * 16 + lh * 4 + r;
                float val = acc[mi][ni][r];
                dst[(size_t)row * HD + cc] = (bf16)val;
                if (arr == 0) sq += val * val;
                else if (arr == 1) sk += val * val;
            }
        }
    }
    #pragma unroll
    for (int off = 32; off > 0; off >>= 1) {
        sq += __shfl_down(sq, off);
        sk += __shfl_down(sk, off);
    }
    if (lane == 0) { rq[w] = sq; rk[w] = sk; }
    __syncthreads();
    if (tid == 0) {
        float a = 0.f, b = 0.f;
        #pragma unroll
        for (int i = 0; i < 4; i++) { a += rq[i]; b += rk[i]; }
        atomicAdd(&sumsq[0], a);
        atomicAdd(&sumsq[1], b);
    }
}

// ---------------- K2: per-graph k^T v via MFMA (node-dim as K) ----------------
// grid 256 blocks (16 graphs x 16 chunks of 512 rows) x 512 threads (8 waves, 2x4).
__global__ __launch_bounds__(512, 1) void k2_kv(
    const bf16* __restrict__ ko, const bf16* __restrict__ vo,
    float* __restrict__ part_kv, float* __restrict__ part_ks)
{
    __shared__ __align__(16) char smem[16640];   // kt[32][130] | vt[32][130]; reused as f32 scr
    bf16 (*kt)[130] = (bf16(*)[130])smem;
    bf16 (*vt)[130] = (bf16(*)[130])(smem + 8320);
    float* scr = (float*)smem;

    const int tid = threadIdx.x, lane = tid & 63, w = tid >> 6;
    const int wr = w >> 2, wc = w & 3;           // 2 m-groups x 4 d-groups
    const int lr = lane & 15, lh = lane >> 4;
    const int b = blockIdx.x >> 4, cch = blockIdx.x & 15;
    const size_t l0 = (size_t)b * LMAX + (size_t)cch * 512;
    const int sr = tid >> 4, sc = tid & 15;      // staging row / col8

    f32x4 acc[4][2];
    #pragma unroll
    for (int mi = 0; mi < 4; mi++)
        #pragma unroll
        for (int ni = 0; ni < 2; ni++)
            acc[mi][ni] = (f32x4){0.f, 0.f, 0.f, 0.f};
    float ks8[8] = {};

    uint4 kk4 = *(const uint4*)&ko[(l0 + sr) * HD + sc * 8];
    uint4 vv4 = *(const uint4*)&vo[(l0 + sr) * HD + sc * 8];

    for (int lt = 0; lt < 512; lt += 32) {
        __syncthreads();   // prev compute done
        #pragma unroll
        for (int j2 = 0; j2 < 4; j2++) {
            *(unsigned int*)&kt[sr][sc * 8 + j2 * 2] = ((const unsigned int*)&kk4)[j2];
            *(unsigned int*)&vt[sr][sc * 8 + j2 * 2] = ((const unsigned int*)&vv4)[j2];
        }
        #pragma unroll
        for (int j = 0; j < 8; j++) ks8[j] += (float)((const bf16*)&kk4)[j];
        __syncthreads();   // tiles published
        if (lt + 32 < 512) {   // prefetch next tile during compute
            kk4 = *(const uint4*)&ko[(l0 + lt + 32 + sr) * HD + sc * 8];
            vv4 = *(const uint4*)&vo[(l0 + lt + 32 + sr) * HD + sc * 8];
        }
        bf16x8 a[4], bb[2];
        #pragma unroll
        for (int mi = 0; mi < 4; mi++) {
            int m = wr * 64 + mi * 16 + lr;
            #pragma unroll
            for (int j = 0; j < 8; j++) a[mi][j] = kt[lh * 8 + j][m];
        }
        #pragma unroll
        for (int ni = 0; ni < 2; ni++) {
            int d = wc * 32 + ni * 16 + lr;
            #pragma unroll
            for (int j = 0; j < 8; j++) bb[ni][j] = vt[lh * 8 + j][d];
        }
        #pragma unroll
        for (int mi = 0; mi < 4; mi++)
            #pragma unroll
            for (int ni = 0; ni < 2; ni++)
                acc[mi][ni] = __builtin_amdgcn_mfma_f32_16x16x32_bf16(
                    a[mi], bb[ni], acc[mi][ni], 0, 0, 0);
    }

    // ks partial: reduce per-thread col-sums across the 32 row-groups
    __syncthreads();
    #pragma unroll
    for (int j = 0; j < 8; j++) scr[tid * 8 + j] = ks8[j];
    __syncthreads();
    if (tid < 128) {
        float s = 0.f;
        #pragma unroll
        for (int g = 0; g < 32; g++)
            s += scr[((g << 4) | (tid >> 3)) * 8 + (tid & 7)];
        part_ks[blockIdx.x * HD + tid] = s;
    }

    float* dst = part_kv + (size_t)blockIdx.x * 16384;
    #pragma unroll
    for (int mi = 0; mi < 4; mi++)
        #pragma unroll
        for (int ni = 0; ni < 2; ni++)
            #pragma unroll
            for (int r = 0; r < 4; r++) {
                int m = wr * 64 + mi * 16 + lh * 4 + r;
                int d = wc * 32 + ni * 16 + lr;
                dst[m * HD + d] = acc[mi][ni][r];
            }
}

// ---------------- K2b: reduce 16 partials/graph, apply s_q*s_k, write kvs^T ----------------
__global__ __launch_bounds__(256, 1) void k2b_reduce(
    const float* __restrict__ part_kv, const float* __restrict__ part_ks,
    const float* __restrict__ sumsq,
    bf16* __restrict__ kvsT, float* __restrict__ ks_sum_s)
{
    const int b = blockIdx.x >> 3, ms = blockIdx.x & 7, tid = threadIdx.x;
    const float s_qk = rsqrtf(sumsq[0]) * rsqrtf(sumsq[1]);

    #pragma unroll
    for (int i = 0; i < 8; i++) {
        int idx = i * 256 + tid;               // 2048 outputs for this m-slice
        int m = ms * 16 + (idx >> 7), d = idx & 127;
        float s = 0.f;
        #pragma unroll
        for (int c = 0; c < 16; c++)
            s += part_kv[((size_t)(b * 16 + c) << 14) + (m << 7) + d];
        kvsT[((size_t)b << 14) + (d << 7) + m] = (bf16)(s * s_qk);
    }
    if (ms == 0 && tid < 128) {
        float s = 0.f;
        #pragma unroll
        for (int c = 0; c < 16; c++)
            s += part_ks[(b * 16 + c) * HD + tid];
        ks_sum_s[b * HD + tid] = s * s_qk;
    }
}

// ---------------- K3: out = (q @ kvsT + 16 v) / (q . ks_sum_s + 16) ----------------
// 70 KB LDS -> 2 blocks/CU; kvsT B-frags read direct from global (L2-hot, 32 KB/graph).
__global__ __launch_bounds__(256, 2) void k3_out(
    const bf16* __restrict__ qo, const bf16* __restrict__ vo,
    const bf16* __restrict__ kvsT, const float* __restrict__ ks_sum_s,
    float* __restrict__ out)
{
    __shared__ bf16 qs[128][136];
    __shared__ bf16 vsh[128][136];
    __shared__ float kss[128];
    __shared__ float denom[128];
    const int tid = threadIdx.x, lane = tid & 63, w = tid >> 6;
    const int lr = lane & 15, lh = lane >> 4;
    const int n0 = blockIdx.x * 128;
    const int b = n0 >> 13;

    #pragma unroll
    for (int i = 0; i < 8; i++) {
        int idx = tid + i * 256;
        int r = idx >> 4, c8 = idx & 15;
        *(bf16x8*)&qs[r][c8 * 8]  = *(const bf16x8*)&qo[(size_t)(n0 + r) * HD + c8 * 8];
        *(bf16x8*)&vsh[r][c8 * 8] = *(const bf16x8*)&vo[(size_t)(n0 + r) * HD + c8 * 8];
    }
    if (tid < 128) kss[tid] = ks_sum_s[b * HD + tid];
    __syncthreads();

    if (tid < 128) {
        float s = 0.f;
        #pragma unroll 8
        for (int m = 0; m < HD; m++) s += (float)qs[tid][m] * kss[m];
        denom[tid] = s + 16.0f;
    }

    f32x4 acc[2][8];
    #pragma unroll
    for (int mi = 0; mi < 2; mi++)
        #pragma unroll
        for (int ni = 0; ni < 8; ni++)
            acc[mi][ni] = (f32x4){0.f, 0.f, 0.f, 0.f};

    #pragma unroll
    for (int k0 = 0; k0 < HD; k0 += 32) {
        bf16x8 a[2], bb[8];
        #pragma unroll
        for (int mi = 0; mi < 2; mi++)
            a[mi] = *(const bf16x8*)&qs[w * 32 + mi * 16 + lr][k0 + lh * 8];
        #pragma unroll
        for (int ni = 0; ni < 8; ni++)
            bb[ni] = *(const bf16x8*)&kvsT[(size_t)b * 16384 + (size_t)(ni * 16 + lr) * HD + k0 + lh * 8];
        #pragma unroll
        for (int mi = 0; mi < 2; mi++)
            #pragma unroll
            for (int ni = 0; ni < 8; ni++)
                acc[mi][ni] = __builtin_amdgcn_mfma_f32_16x16x32_bf16(
                    a[mi], bb[ni], acc[mi][ni], 0, 0, 0);
    }
    __syncthreads();   // denom ready

    #pragma unroll
    for (int mi = 0; mi < 2; mi++) {
        #pragma unroll
        for (int ni = 0; ni < 8; ni++) {
            int col = ni * 16 + lr;
            #pragma unroll
            for (int r = 0; r < 4; r++) {
                int row = w * 32 + mi * 16 + lh * 4 + r;
                float vv = (float)vsh[row][col];
                out[(size_t)(n0 + row) * HD + col] =
                    (acc[mi][ni][r] + 16.0f * vv) / denom[row];
            }
        }
    }
}

// ---------------- launch ----------------
extern "C" void kernel_launch(void* const* d_in, const int* in_sizes, int n_in,
                              void* d_out, int out_size, void* d_ws, size_t ws_size,
                              hipStream_t stream)
{
    const float* x  = (const float*)d_in[0];
    const float* Wq = (const float*)d_in[1];
    const float* Wk = (const float*)d_in[2];
    const float* Wv = (const float*)d_in[3];

    char* ws = (char*)d_ws;
    const size_t Q_OFF   = 0;                       // 131072*128*2 = 33554432
    const size_t K_OFF   = 33554432;
    const size_t V_OFF   = 67108864;
    const size_t PKV_OFF = 100663296;               // 256*16384*4 = 16777216
    const size_t PKS_OFF = 117440512;               // 256*128*4   = 131072
    const size_t KVS_OFF = 117571584;               // 16*16384*2  = 524288
    const size_t KSS_OFF = 118095872;               // 16*128*4    = 8192
    const size_t SSQ_OFF = 118104064;               // 2*4
    const size_t NEED    = 118104072;
    if (ws_size < NEED) return;

    bf16*  qo      = (bf16*)(ws + Q_OFF);
    bf16*  ko      = (bf16*)(ws + K_OFF);
    bf16*  vo      = (bf16*)(ws + V_OFF);
    float* part_kv = (float*)(ws + PKV_OFF);
    float* part_ks = (float*)(ws + PKS_OFF);
    bf16*  kvsT    = (bf16*)(ws + KVS_OFF);
    float* ks_sum  = (float*)(ws + KSS_OFF);
    float* sumsq   = (float*)(ws + SSQ_OFF);
    // wsW (393216 B) overlaps part_kv region: live only k0->k1, dead before k2 writes part_kv
    bf16*  wsW     = (bf16*)(ws + PKV_OFF);

    hipMemsetAsync(sumsq, 0, 8, stream);
    k0_prep<<<dim3(96), dim3(256), 0, stream>>>(Wq, Wk, Wv, wsW);
    k1_proj<<<dim3(N_NODES / 64), dim3(256), 0, stream>>>(x, wsW, qo, ko, vo, sumsq);
    k2_kv<<<dim3(256), dim3(512), 0, stream>>>(ko, vo, part_kv, part_ks);
    k2b_reduce<<<dim3(128), dim3(256), 0, stream>>>(part_kv, part_ks, sumsq, kvsT, ks_sum);
    k3_out<<<dim3(N_NODES / 128), dim3(256), 0, stream>>>(qo, vo, kvsT, ks_sum, (float*)d_out);
}